// Round 8
// baseline (165.633 us; speedup 1.0000x reference)
//
#include <hip/hip_runtime.h>
#include <math.h>

#define SS 8192
#define HH 2048
#define NBLK 512
#define NTHR 512
#define NP 4

// Persistent coherent scratch. All cross-block data moves via agent-scope
// atomics (coherent point, bypasses non-coherent per-XCD L2s) -> no fences
// needed (validated R5: fenced barrier ~50us, fence-free ~5).
// g_part parity double-buffered: launch L accumulates into bank L&1, re-zeroes
// it post-use; the other bank is clean (both zero at module load). Parity
// derives from the barrier counter (quiescent between launches = L*2*NBLK;
// early barrier-1 arrivals add < 2*NBLK, so floor-division is race-free).
__device__ unsigned g_ctr = 0;                    // monotone barrier arrivals
__device__ unsigned g_rel = 0;                    // monotone release epoch
__device__ float g_part[2][NP][HH] = {};          // colsum partial banks
__device__ unsigned long long g_pair[NBLK];       // packed (m_b, s_b)

// Fence-free grid barrier (R5-validated). __syncthreads() drains vmcnt per
// wave, so prior atomics are retired at the coherent point before the
// leader's fetch_add; coherent reads after the barrier must observe them.
// Deadlock-safe: 512 blocks, VGPR<=128 (launch_bounds(512,4)) and ~12 KB LDS
// -> 2 blocks/CU on 256 CUs -> all 512 co-resident.
__device__ __forceinline__ void grid_barrier() {
    __syncthreads();
    if (threadIdx.x == 0) {
        unsigned old = __hip_atomic_fetch_add(&g_ctr, 1u, __ATOMIC_RELAXED,
                                              __HIP_MEMORY_SCOPE_AGENT);
        unsigned epoch = old / NBLK;
        if (old % NBLK == NBLK - 1u) {
            __hip_atomic_store(&g_rel, epoch + 1u, __ATOMIC_RELAXED,
                               __HIP_MEMORY_SCOPE_AGENT);
        } else {
            while (__hip_atomic_load(&g_rel, __ATOMIC_RELAXED,
                                     __HIP_MEMORY_SCOPE_AGENT) <= epoch)
                __builtin_amdgcn_s_sleep(8);
        }
    }
    asm volatile("" ::: "memory");   // compiler-only ordering
    __syncthreads();
}

__global__ __launch_bounds__(NTHR, 4) void fused_kernel(
    const float* __restrict__ enc,
    const float* __restrict__ W,
    const float* __restrict__ w,
    float* __restrict__ out)
{
    const int b    = blockIdx.x;
    const int t    = threadIdx.x;
    const int wave = t >> 6;
    const int lane = t & 63;

    __shared__ float v2s[HH];        // 8 KB reduced v2
    __shared__ float srow[16];       // this block's raw scores
    __shared__ float mv[NBLK];       // pair maxes   (2 KB)
    __shared__ float sv[NBLK];       // pair sums    (2 KB)
    __shared__ float red[2];
    __shared__ unsigned sh_par;

    if (t == 0) {
        unsigned c = __hip_atomic_load(&g_ctr, __ATOMIC_RELAXED,
                                       __HIP_MEMORY_SCOPE_AGENT);
        sh_par = (c / (2u * NBLK)) & 1u;
    }
    __syncthreads();
    const unsigned par = sh_par;

    // ---- Prefetch, sized to the 128-VGPR cap (R7's 170-VGPR version got
    // sunk by the compiler). W first (4 loads), enc second (16 loads):
    // P1's waitcnt then only drains wv while enc keeps streaming through
    // P1 compute + barrier-1 wait. sched_barrier(0) pins the issue point.
    const int row0 = b * 4;
    const float4* wbase =
        (const float4*)(W + (size_t)row0 * (2 * HH) + HH) + t;
    float4 wv[4];
#pragma unroll
    for (int j = 0; j < 4; ++j)
        wv[j] = wbase[(size_t)j * ((2 * HH) / 4)];

    const int rbase = b * 16 + wave * 2;
    float4 er[2][8];
#pragma unroll
    for (int rr = 0; rr < 2; ++rr) {
        const float4* e = (const float4*)(enc + (size_t)(rbase + rr) * HH);
#pragma unroll
        for (int i = 0; i < 8; ++i)
            er[rr][i] = e[lane + i * 64];
    }
    __builtin_amdgcn_sched_barrier(0);

    // ---- Phase 1: colsum partial. Block b: rows 4b..4b+3, all 2048 cols.
    // atomicAdd into bank par, sub-bank b&3 -> 128 adds/address, fire-and-
    // forget at the coherent point. ----
    {
        float4 acc = {0.f, 0.f, 0.f, 0.f};
#pragma unroll
        for (int j = 0; j < 4; ++j) {
            float wj = w[row0 + j];              // block-uniform -> s_load
            acc.x += wj * wv[j].x; acc.y += wj * wv[j].y;
            acc.z += wj * wv[j].z; acc.w += wj * wv[j].w;
        }
        float* dst = &g_part[par][b & 3][t * 4];
        atomicAdd(dst + 0, acc.x);
        atomicAdd(dst + 1, acc.y);
        atomicAdd(dst + 2, acc.z);
        atomicAdd(dst + 3, acc.w);
    }

    grid_barrier();

    // ---- Phase 2a: v2 -> LDS. 16 coherent loads/thread, wave-coalesced
    // (consecutive t -> consecutive addresses; R6's lane-strided coherent
    // loads were the regression - never again). ----
#pragma unroll
    for (int k = 0; k < 4; ++k) {
        const int c = t + k * 512;
        float s = 0.0f;
#pragma unroll
        for (int p = 0; p < NP; ++p)
            s += __hip_atomic_load(&g_part[par][p][c], __ATOMIC_RELAXED,
                                   __HIP_MEMORY_SCOPE_AGENT);
        v2s[c] = s;
    }
    __syncthreads();

    // ---- Phase 2b: rowdot from register-held enc (pure ALU). ----
    {
        const float4* v4 = (const float4*)v2s;
        float4 vf[8];
#pragma unroll
        for (int i = 0; i < 8; ++i) vf[i] = v4[lane + i * 64];

#pragma unroll
        for (int rr = 0; rr < 2; ++rr) {
            float acc = 0.0f;
#pragma unroll
            for (int i = 0; i < 8; ++i) {
                acc += er[rr][i].x * vf[i].x + er[rr][i].y * vf[i].y
                     + er[rr][i].z * vf[i].z + er[rr][i].w * vf[i].w;
            }
#pragma unroll
            for (int off = 32; off > 0; off >>= 1)
                acc += __shfl_down(acc, off);
            if (lane == 0) srow[wave * 2 + rr] = acc;
        }
    }
    __syncthreads();

    // ---- Publish per-block (max, sumexp) over its 16 scores. ----
    if (wave == 0) {
        float v = (lane < 16) ? srow[lane] : -INFINITY;
        float m = v;
#pragma unroll
        for (int off = 1; off < 64; off <<= 1)
            m = fmaxf(m, __shfl_xor(m, off));
        float s = (lane < 16) ? __expf(v - m) : 0.0f;
#pragma unroll
        for (int off = 1; off < 64; off <<= 1)
            s += __shfl_xor(s, off);
        if (lane == 0) {
            unsigned long long p =
                ((unsigned long long)__float_as_uint(s) << 32) |
                (unsigned long long)__float_as_uint(m);
            __hip_atomic_store(&g_pair[b], p, __ATOMIC_RELAXED,
                               __HIP_MEMORY_SCOPE_AGENT);
        }
    }

    grid_barrier();

    // ---- Re-zero own slice of bank par (unread after barrier 2; next
    // launch uses the other bank). 16 atomic stores/block = 8192 total. ----
    if (t < 16) {
        const int idx = b * 16 + t;
        __hip_atomic_store(&g_part[par][idx >> 11][idx & 2047], 0.0f,
                           __ATOMIC_RELAXED, __HIP_MEMORY_SCOPE_AGENT);
    }

    // ---- Phase 3: combine 512 pairs (coalesced coherent loads), write
    // own 16-element output slice from srow (still in LDS). ----
    {
        unsigned long long p = __hip_atomic_load(&g_pair[t], __ATOMIC_RELAXED,
                                                 __HIP_MEMORY_SCOPE_AGENT);
        mv[t] = __uint_as_float((unsigned)(p & 0xffffffffu));
        sv[t] = __uint_as_float((unsigned)(p >> 32));
    }
    __syncthreads();
    if (wave == 0) {
        float m8 = -INFINITY;
#pragma unroll
        for (int k = 0; k < 8; ++k)
            m8 = fmaxf(m8, mv[lane + k * 64]);
#pragma unroll
        for (int off = 32; off > 0; off >>= 1)
            m8 = fmaxf(m8, __shfl_xor(m8, off));
        if (lane == 0) red[0] = m8;
    }
    __syncthreads();
    const float M = red[0];
    if (wave == 0) {
        float s8 = 0.0f;
#pragma unroll
        for (int k = 0; k < 8; ++k)
            s8 += sv[lane + k * 64] * __expf(mv[lane + k * 64] - M);
#pragma unroll
        for (int off = 32; off > 0; off >>= 1)
            s8 += __shfl_xor(s8, off);
        if (lane == 0) red[1] = s8;
    }
    __syncthreads();
    const float inv = 1.0f / red[1];

    if (t < 16)
        out[b * 16 + t] = __expf(srow[t] - M) * inv;
}

extern "C" void kernel_launch(void* const* d_in, const int* in_sizes, int n_in,
                              void* d_out, int out_size, void* d_ws, size_t ws_size,
                              hipStream_t stream) {
    const float* enc   = (const float*)d_in[0];  // (S,1,H) -> (S,H)
    // d_in[1] = hidden : constant score shift -> cancels in softmax
    const float* W_att = (const float*)d_in[2];  // (H, 2H)
    // d_in[3] = b_att  : constant shift -> cancels
    const float* w     = (const float*)d_in[4];  // (1, H)

    float* out = (float*)d_out;                  // 8192 floats (1,1,S)

    hipLaunchKernelGGL(fused_kernel, dim3(NBLK), dim3(NTHR), 0, stream,
                       enc, W_att, w, out);
}

// Round 9
// 143.405 us; speedup vs baseline: 1.1550x; 1.1550x over previous
//
#include <hip/hip_runtime.h>
#include <math.h>

#define SS 8192
#define HH 2048
#define NBLK 256
#define NTHR 512
#define NP 4

// Persistent coherent scratch. All cross-block data moves via agent-scope
// atomics (coherent point, bypasses non-coherent per-XCD L2s) -> no fences
// (validated R5: fenced barrier ~50us, fence-free ~5).
// g_part parity double-buffered: launch L accumulates into bank L&1 and
// re-zeroes it after barrier 2; the other bank is clean (both zero at module
// load). Parity from the quiescent barrier counter (= launches*2*NBLK).
__device__ unsigned g_ctr = 0;                    // monotone barrier arrivals
__device__ unsigned g_rel = 0;                    // monotone release epoch
__device__ float g_part[2][NP][HH] = {};          // colsum partial banks
__device__ unsigned long long g_pair[NBLK];       // packed (m_b, s_b)

// Fence-free grid barrier (R5-validated, 256 arrivals ~5us). __syncthreads()
// drains vmcnt per wave, so prior atomics are retired at the coherent point
// before the leader's fetch_add; coherent reads after the barrier observe
// them. Deadlock-safe: 256 blocks, >=1 block/CU on 256 CUs -> co-resident.
__device__ __forceinline__ void grid_barrier() {
    __syncthreads();
    if (threadIdx.x == 0) {
        unsigned old = __hip_atomic_fetch_add(&g_ctr, 1u, __ATOMIC_RELAXED,
                                              __HIP_MEMORY_SCOPE_AGENT);
        unsigned epoch = old / NBLK;
        if (old % NBLK == NBLK - 1u) {
            __hip_atomic_store(&g_rel, epoch + 1u, __ATOMIC_RELAXED,
                               __HIP_MEMORY_SCOPE_AGENT);
        } else {
            while (__hip_atomic_load(&g_rel, __ATOMIC_RELAXED,
                                     __HIP_MEMORY_SCOPE_AGENT) <= epoch)
                __builtin_amdgcn_s_sleep(8);
        }
    }
    asm volatile("" ::: "memory");   // compiler-only ordering
    __syncthreads();
}

__global__ __launch_bounds__(NTHR, 2) void fused_kernel(
    const float* __restrict__ enc,
    const float* __restrict__ W,
    const float* __restrict__ w,
    float* __restrict__ out)
{
    const int b    = blockIdx.x;
    const int t    = threadIdx.x;
    const int wave = t >> 6;
    const int lane = t & 63;

    __shared__ float v2s[HH];        // 8 KB reduced v2
    __shared__ float srow[32];       // this block's raw scores
    __shared__ float mv[NBLK];       // pair maxes (1 KB)
    __shared__ float sv[NBLK];       // pair sums  (1 KB)
    __shared__ float red[2];
    __shared__ unsigned sh_par;

    if (t == 0) {
        unsigned c = __hip_atomic_load(&g_ctr, __ATOMIC_RELAXED,
                                       __HIP_MEMORY_SCOPE_AGENT);
        sh_par = (c / (2u * NBLK)) & 1u;
    }
    __syncthreads();
    const unsigned par = sh_par;

    // ---- Phase 1: colsum partial. Block b: rows 8b..8b+7, all 2048 cols.
    // Batch all 8 W float4 loads (independent -> 8 outstanding, W is mostly
    // L3-resident), then FMA, then 4 atomicAdds into bank par (64/address,
    // R5-proven contention). No cross-barrier register carrying. ----
    {
        const int row0 = b * 8;
        const float4* wbase =
            (const float4*)(W + (size_t)row0 * (2 * HH) + HH) + t;
        float4 wv[8];
#pragma unroll
        for (int j = 0; j < 8; ++j)
            wv[j] = wbase[(size_t)j * ((2 * HH) / 4)];

        float4 acc = {0.f, 0.f, 0.f, 0.f};
#pragma unroll
        for (int j = 0; j < 8; ++j) {
            float wj = w[row0 + j];              // block-uniform -> s_load
            acc.x += wj * wv[j].x; acc.y += wj * wv[j].y;
            acc.z += wj * wv[j].z; acc.w += wj * wv[j].w;
        }
        float* dst = &g_part[par][b & 3][t * 4];
        atomicAdd(dst + 0, acc.x);
        atomicAdd(dst + 1, acc.y);
        atomicAdd(dst + 2, acc.z);
        atomicAdd(dst + 3, acc.w);
    }

    grid_barrier();

    // ---- Phase 2a: v2 -> LDS. 16 coherent loads/thread, wave-coalesced
    // (consecutive t -> consecutive addresses). ----
#pragma unroll
    for (int k = 0; k < 4; ++k) {
        const int c = t + k * 512;
        float s = 0.0f;
#pragma unroll
        for (int p = 0; p < NP; ++p)
            s += __hip_atomic_load(&g_part[par][p][c], __ATOMIC_RELAXED,
                                   __HIP_MEMORY_SCOPE_AGENT);
        v2s[c] = s;
    }
    __syncthreads();

    // ---- Phase 2b: rowdot. THE fix for the 1.1 TB/s in-flight ceiling:
    // batch ALL 32 enc float4 loads (er[4][8] = 128 VGPR = 2 KB/lane in
    // flight -> ~256 KB/CU, >>20 KB Little's-law need) entirely inside the
    // phase (no barrier to sink across), then compute. launch_bounds(512,2)
    // caps VGPR at 256 so ~190 live regs fit. ----
    {
        const float4* v4 = (const float4*)v2s;
        float4 vf[8];
#pragma unroll
        for (int i = 0; i < 8; ++i) vf[i] = v4[lane + i * 64];

        const int rbase = b * 32 + wave * 4;
        float4 er[4][8];
#pragma unroll
        for (int rr = 0; rr < 4; ++rr) {
            const float4* e =
                (const float4*)(enc + (size_t)(rbase + rr) * HH);
#pragma unroll
            for (int i = 0; i < 8; ++i)
                er[rr][i] = e[lane + i * 64];
        }

#pragma unroll
        for (int rr = 0; rr < 4; ++rr) {
            float acc = 0.0f;
#pragma unroll
            for (int i = 0; i < 8; ++i) {
                acc += er[rr][i].x * vf[i].x + er[rr][i].y * vf[i].y
                     + er[rr][i].z * vf[i].z + er[rr][i].w * vf[i].w;
            }
#pragma unroll
            for (int off = 32; off > 0; off >>= 1)
                acc += __shfl_down(acc, off);
            if (lane == 0) srow[wave * 4 + rr] = acc;
        }
    }
    __syncthreads();

    // ---- Publish per-block (max, sumexp) over its 32 scores. ----
    if (wave == 0) {
        float v = (lane < 32) ? srow[lane] : -INFINITY;
        float m = v;
#pragma unroll
        for (int off = 1; off < 64; off <<= 1)
            m = fmaxf(m, __shfl_xor(m, off));
        float s = (lane < 32) ? __expf(v - m) : 0.0f;
#pragma unroll
        for (int off = 1; off < 64; off <<= 1)
            s += __shfl_xor(s, off);
        if (lane == 0) {
            unsigned long long p =
                ((unsigned long long)__float_as_uint(s) << 32) |
                (unsigned long long)__float_as_uint(m);
            __hip_atomic_store(&g_pair[b], p, __ATOMIC_RELAXED,
                               __HIP_MEMORY_SCOPE_AGENT);
        }
    }

    grid_barrier();

    // ---- Re-zero own slice of bank par (unread after barrier 2; next
    // launch uses the other bank). 32 atomic stores/block = 8192 total. ----
    if (t < 32) {
        const int idx = b * 32 + t;
        __hip_atomic_store(&g_part[par][idx >> 11][idx & 2047], 0.0f,
                           __ATOMIC_RELAXED, __HIP_MEMORY_SCOPE_AGENT);
    }

    // ---- Phase 3: combine 256 pairs (coalesced coherent loads), write own
    // 32-element output slice from srow (still in LDS). ----
    if (t < NBLK) {
        unsigned long long p = __hip_atomic_load(&g_pair[t], __ATOMIC_RELAXED,
                                                 __HIP_MEMORY_SCOPE_AGENT);
        mv[t] = __uint_as_float((unsigned)(p & 0xffffffffu));
        sv[t] = __uint_as_float((unsigned)(p >> 32));
    }
    __syncthreads();
    if (wave == 0) {
        float m4 = fmaxf(fmaxf(mv[lane], mv[lane + 64]),
                         fmaxf(mv[lane + 128], mv[lane + 192]));
#pragma unroll
        for (int off = 32; off > 0; off >>= 1)
            m4 = fmaxf(m4, __shfl_xor(m4, off));
        if (lane == 0) red[0] = m4;
    }
    __syncthreads();
    const float M = red[0];
    if (wave == 0) {
        float s4 = sv[lane]       * __expf(mv[lane]       - M)
                 + sv[lane + 64]  * __expf(mv[lane + 64]  - M)
                 + sv[lane + 128] * __expf(mv[lane + 128] - M)
                 + sv[lane + 192] * __expf(mv[lane + 192] - M);
#pragma unroll
        for (int off = 32; off > 0; off >>= 1)
            s4 += __shfl_xor(s4, off);
        if (lane == 0) red[1] = s4;
    }
    __syncthreads();
    const float inv = 1.0f / red[1];

    if (t < 32)
        out[b * 32 + t] = __expf(srow[t] - M) * inv;
}

extern "C" void kernel_launch(void* const* d_in, const int* in_sizes, int n_in,
                              void* d_out, int out_size, void* d_ws, size_t ws_size,
                              hipStream_t stream) {
    const float* enc   = (const float*)d_in[0];  // (S,1,H) -> (S,H)
    // d_in[1] = hidden : constant score shift -> cancels in softmax
    const float* W_att = (const float*)d_in[2];  // (H, 2H)
    // d_in[3] = b_att  : constant shift -> cancels
    const float* w     = (const float*)d_in[4];  // (1, H)

    float* out = (float*)d_out;                  // 8192 floats (1,1,S)

    hipLaunchKernelGGL(fused_kernel, dim3(NBLK), dim3(NTHR), 0, stream,
                       enc, W_att, w, out);
}

// Round 10
// 121.587 us; speedup vs baseline: 1.3623x; 1.1794x over previous
//
#include <hip/hip_runtime.h>
#include <math.h>

#define SS 8192
#define HH 2048
#define NP 4

// Persistent device-global scratch (zero at module load). g_v2p is
// re-zeroed by K3 at the end of every launch; stream order serializes
// K1(L+1) after K3(L), and end-of-kernel release / start-of-kernel acquire
// handle cross-kernel visibility (R2/R3-proven: atomicAdd in K1 -> plain
// loads in K2 passed). No memset kernel, no ws usage at all.
__device__ float g_v2p[NP][HH];     // colsum partial slots
__device__ float g_sc[SS];          // raw scores

// ---- K1: colsum. grid (2,128), block 256. Block (bx,by): cols bx*1024
// + 4t.., rows by*16.. Register pre-accumulate 16 rows (float4, batched
// independent loads), then 4 atomicAdds into slot by&3 (32-deep chains,
// proven contention level). 16 MB stream across 256 blocks. ----
__global__ __launch_bounds__(256) void colsum_kernel(
    const float* __restrict__ W,
    const float* __restrict__ w)
{
    const int t       = threadIdx.x;
    const int colBase = blockIdx.x * 1024;
    const int row0    = blockIdx.y * 16;
    const float4* base =
        (const float4*)(W + (size_t)row0 * (2 * HH) + HH + colBase) + t;

    float4 wv[16];
#pragma unroll
    for (int j = 0; j < 16; ++j)
        wv[j] = base[(size_t)j * ((2 * HH) / 4)];

    float4 acc = {0.f, 0.f, 0.f, 0.f};
#pragma unroll
    for (int j = 0; j < 16; ++j) {
        const float wj = w[row0 + j];           // block-uniform -> s_load
        acc.x += wj * wv[j].x; acc.y += wj * wv[j].y;
        acc.z += wj * wv[j].z; acc.w += wj * wv[j].w;
    }
    float* dst = &g_v2p[blockIdx.y & (NP - 1)][colBase + t * 4];
    atomicAdd(dst + 0, acc.x);
    atomicAdd(dst + 1, acc.y);
    atomicAdd(dst + 2, acc.z);
    atomicAdd(dst + 3, acc.w);
}

// ---- K2: rowdot. grid 1024, block 512 = 8 waves, 1 row/wave ->
// 24+ waves/CU resident (VGPR ~90): 3x the latency hiding of the fused
// attempts. Each wave issues its 8 enc float4 loads FIRST (they stream
// while the v2 slot-reduce -> LDS fill completes), then dots against the
// LDS-held v2. ----
__global__ __launch_bounds__(512) void rowdot_kernel(
    const float* __restrict__ enc)
{
    __shared__ float v2s[HH];
    const int t    = threadIdx.x;
    const int wave = t >> 6;
    const int lane = t & 63;
    const int row  = blockIdx.x * 8 + wave;

    // enc loads issued first; consumed last (vmcnt covers the overlap).
    const float4* e = (const float4*)(enc + (size_t)row * HH);
    float4 er[8];
#pragma unroll
    for (int i = 0; i < 8; ++i)
        er[i] = e[lane + i * 64];

    // v2 = sum of NP slots; 512 thr x float4 = 2048 floats, coalesced.
    {
        float4 s4 = {0.f, 0.f, 0.f, 0.f};
#pragma unroll
        for (int p = 0; p < NP; ++p) {
            float4 a = ((const float4*)g_v2p[p])[t];
            s4.x += a.x; s4.y += a.y; s4.z += a.z; s4.w += a.w;
        }
        ((float4*)v2s)[t] = s4;
    }
    __syncthreads();

    const float4* v4 = (const float4*)v2s;
    float acc = 0.0f;
#pragma unroll
    for (int i = 0; i < 8; ++i) {
        const float4 vf = v4[lane + i * 64];
        acc += er[i].x * vf.x + er[i].y * vf.y
             + er[i].z * vf.z + er[i].w * vf.w;
    }
#pragma unroll
    for (int off = 32; off > 0; off >>= 1)
        acc += __shfl_down(acc, off);
    if (lane == 0) g_sc[row] = acc;
}

// ---- K3: softmax. grid 512, block 256. Every block redundantly reduces
// all 8192 scores (32 KB, L2/L3-resident) and writes its own 16-element
// output slice. Blocks 0..7 also re-zero g_v2p for the next launch
// (stream-ordered after K2; K3 never reads g_v2p -> no race). ----
__global__ __launch_bounds__(256) void softmax_kernel(
    float* __restrict__ out)
{
    __shared__ float red[4];
    const int t    = threadIdx.x;
    const int lane = t & 63;
    const int wid  = t >> 6;
    const int b    = blockIdx.x;

    if (b < 8)                      // 8 blocks x 256 thr x float4 = 8192
        ((float4*)g_v2p)[b * 256 + t] = make_float4(0.f, 0.f, 0.f, 0.f);

    float vals[32];
    float m = -INFINITY;
#pragma unroll
    for (int i = 0; i < 32; ++i) {
        vals[i] = g_sc[t + i * 256];
        m = fmaxf(m, vals[i]);
    }
#pragma unroll
    for (int off = 1; off < 64; off <<= 1)
        m = fmaxf(m, __shfl_xor(m, off));
    if (lane == 0) red[wid] = m;
    __syncthreads();
    m = fmaxf(fmaxf(red[0], red[1]), fmaxf(red[2], red[3]));

    float s = 0.0f;
#pragma unroll
    for (int i = 0; i < 32; ++i)
        s += __expf(vals[i] - m);
#pragma unroll
    for (int off = 1; off < 64; off <<= 1)
        s += __shfl_xor(s, off);
    __syncthreads();                 // everyone done reading red (max)
    if (lane == 0) red[wid] = s;
    __syncthreads();
    const float inv = 1.0f / (red[0] + red[1] + red[2] + red[3]);

    if (t < 16) {
        const int e = b * 16 + t;
        out[e] = __expf(g_sc[e] - m) * inv;
    }
}

extern "C" void kernel_launch(void* const* d_in, const int* in_sizes, int n_in,
                              void* d_out, int out_size, void* d_ws, size_t ws_size,
                              hipStream_t stream) {
    const float* enc   = (const float*)d_in[0];  // (S,1,H) -> (S,H)
    // d_in[1] = hidden : constant score shift -> cancels in softmax
    const float* W_att = (const float*)d_in[2];  // (H, 2H)
    // d_in[3] = b_att  : constant shift -> cancels
    const float* w     = (const float*)d_in[4];  // (1, H)

    float* out = (float*)d_out;                  // 8192 floats (1,1,S)

    hipLaunchKernelGGL(colsum_kernel,  dim3(2, 128), dim3(256), 0, stream,
                       W_att, w);
    hipLaunchKernelGGL(rowdot_kernel,  dim3(1024),   dim3(512), 0, stream,
                       enc);
    hipLaunchKernelGGL(softmax_kernel, dim3(512),    dim3(256), 0, stream,
                       out);
}